// Round 5
// baseline (86.511 us; speedup 1.0000x reference)
//
#include <hip/hip_runtime.h>

#define NQ  8
#define HID 512

// Closed-form evaluation of the reference:
//  - H^8|0> = |+>^8; per-sample RX embedding = global phase (dead) => output
//    row is identical for all B samples.
//  - RY(w0_q) on |+> gives <Z_q> = -sin(w0_q); RZ is diagonal (dead in probs).
//  - Reference's _apply_cnot flips a size-1 axis for all adjacent ring CNOTs
//    (no-ops); only CNOT(wire7 -> wire0) is real, a classical permutation:
//      ev[0] = <Z0 Z7> = sin(w0_0) sin(w0_7); ev[k>=1] = -sin(w0_k).
//  - out[r][h] = sum_q ev[q] W_out[h][q] + b_out[h]  (float32, broadcast over r).
__global__ __launch_bounds__(256)
void vqc_closed_kernel(const float* __restrict__ vqc_w,   // [2][8] f32
                       const float* __restrict__ W_out,   // [512][8] f32
                       const float* __restrict__ b_out,   // [512] f32
                       float* __restrict__ out,           // [B][512] f32
                       int B, int rows_per_block)
{
    const int t = threadIdx.x;

    float ev[NQ];
    {
        const float s0 = sinf(vqc_w[0]);
        const float s7 = sinf(vqc_w[7]);
        ev[0] = s0 * s7;
        #pragma unroll
        for (int k = 1; k < NQ; ++k) ev[k] = -sinf(vqc_w[k]);
    }

    // Thread owns h in [4c, 4c+4), c = t & 127: 4 dots + bias -> one float4.
    const int c = t & 127;
    float acc[4];
    #pragma unroll
    for (int i = 0; i < 4; ++i) acc[i] = b_out[4 * c + i];
    #pragma unroll
    for (int q = 0; q < NQ; ++q) {
        const float e = ev[q];
        #pragma unroll
        for (int i = 0; i < 4; ++i)
            acc[i] += e * W_out[(4 * c + i) * NQ + q];
    }
    float4 v = make_float4(acc[0], acc[1], acc[2], acc[3]);

    // Broadcast-store: each row = 128 float4 (2 KB). Lanes c=0..127 (2 waves)
    // cover one row contiguously; 256 threads -> 2 rows per iteration.
    float4* __restrict__ out4 = (float4*)out;
    const int r0 = blockIdx.x * rows_per_block;
    const int rsub = t >> 7;   // 0..1
    for (int r = r0 + rsub; r < r0 + rows_per_block; r += 2) {
        if (r < B) out4[(size_t)r * 128 + c] = v;
    }
}

extern "C" void kernel_launch(void* const* d_in, const int* in_sizes, int n_in,
                              void* d_out, int out_size, void* d_ws, size_t ws_size,
                              hipStream_t stream)
{
    // Select pointers by unique element counts (robust to input ordering):
    //   vqc_weights: 16, W_out: 512*8 = 4096, b_out: 512.
    const float* vqc_w = nullptr;
    const float* W_out = nullptr;
    const float* b_out = nullptr;
    for (int i = 0; i < n_in; ++i) {
        if (in_sizes[i] == 2 * NQ)        vqc_w = (const float*)d_in[i];
        else if (in_sizes[i] == HID * NQ) W_out = (const float*)d_in[i];
        else if (in_sizes[i] == HID)      b_out = (const float*)d_in[i];
    }
    if (!vqc_w) vqc_w = (const float*)d_in[4];
    if (!W_out) W_out = (const float*)d_in[5];
    if (!b_out) b_out = (const float*)d_in[6];

    float* out = (float*)d_out;               // float32 output (reference dtype)

    const int B = out_size / HID;             // 8192
    const int grid = 256;                     // 1 block per CU
    const int rows_per_block = (B + grid - 1) / grid;   // 32

    vqc_closed_kernel<<<dim3(grid), dim3(256), 0, stream>>>(
        vqc_w, W_out, b_out, out, B, rows_per_block);
}